// Round 12
// baseline (210.678 us; speedup 1.0000x reference)
//
#include <hip/hip_runtime.h>
#include <math.h>

typedef unsigned short u16;
typedef unsigned int   u32;

typedef __attribute__((ext_vector_type(8))) _Float16 f16x8;
typedef __attribute__((ext_vector_type(4))) float    f32x4;

// ---------- constants ----------
#define NB   2
#define C    256
#define H    96
#define W    96
#define HW   (H*W)          // 9216
#define HP   98
#define OC   256
#define KDIM (9*C)          // 2304
#define NS   (NB*HW)        // 18432 spatial columns

// ws layout (bytes)
#define XP_OFF    0                      // 2*98*98*256 fp32 = 19668992
#define AHI_OFF   19668992               // 256*2304 f16     = 1179648
#define ALO_OFF   20848640               // 256*2304 f16     = 1179648
#define A2HI_OFF  22028288               // 32*2304 f16      = 147456
#define A2LO_OFF  22175744               // 32*2304 f16      = 147456
#define OFF2_OFF  22323200               // 21*18432 fp32    = 1548288
#define IDX_OFF   23871488               // 9*18432*4 int    = 2654208
#define G_OFF     26525696               // 9*18432*4 fp32   = 2654208
// end 29179904

__device__ __forceinline__ u16 h2u(_Float16 h) {
  return __builtin_bit_cast(unsigned short, h);
}
__device__ __forceinline__ void split16(float v, u16& hi, u16& lo) {
  _Float16 h = (_Float16)v;        // v_cvt_f16_f32, RNE
  float r = v - (float)h;          // exact residual
  _Float16 l = (_Float16)r;
  hi = h2u(h); lo = h2u(l);
}
// LDS-only barrier: waits lgkmcnt(0) but does NOT drain vmcnt.
__device__ __forceinline__ void sync_lds() {
  asm volatile("s_waitcnt lgkmcnt(0)\n\ts_barrier" ::: "memory");
}

// ================= prep: pad_pack(0..1151) | pack_A(1152..1439) | pack_A2(1440..1475) =================
__global__ __launch_bounds__(256) void prep1(
    const float* __restrict__ x, const float* __restrict__ w_p,
    const float* __restrict__ w_ad, const float* __restrict__ w_conv,
    float* __restrict__ xp,
    u16* __restrict__ A_hi, u16* __restrict__ A_lo,
    u16* __restrict__ A2_hi, u16* __restrict__ A2_lo) {
  __shared__ float smem[64*65];
  int bx = blockIdx.x;
  int tid = threadIdx.x;

  if (bx < 1152) {
    // ---- NCHW fp32 -> padded NHWC fp32 (borders pre-zeroed by memset) ----
    int pb = bx;
    int n = pb / 576; int r = pb % 576;
    int cb = r / 144; int hwb = r % 144;
    int c0 = cb * 64, hw0 = hwb * 64;
    int ii = tid & 63; int cl4 = tid >> 6;
    #pragma unroll
    for (int r2 = 0; r2 < 16; r2++) {
      int c_l = cl4*16 + r2;
      smem[c_l*65 + ii] = x[(size_t)(n*C + c0 + c_l)*HW + hw0 + ii];
    }
    __syncthreads();
    int hw = hw0 + ii;
    int h = hw / W, w = hw % W;
    float* dst = xp + ((size_t)(n*HP + h + 1)*HP + (w + 1))*C + c0 + cl4*16;
    #pragma unroll
    for (int q = 0; q < 4; q++) {
      *(float4*)(dst + q*4) = make_float4(smem[(cl4*16 + q*4 + 0)*65 + ii],
                                          smem[(cl4*16 + q*4 + 1)*65 + ii],
                                          smem[(cl4*16 + q*4 + 2)*65 + ii],
                                          smem[(cl4*16 + q*4 + 3)*65 + ii]);
    }

  } else if (bx < 1440) {
    // ---- pack+split w_conv into MFMA-fragment-tiled A_hi/A_lo (r8/r9-proven) ----
    // e = ((((mo*72+itg)*2+mw)*4+mi)*64+lane)*8 + j holds
    //   A[o = mo*128+mw*64+mi*16+(lane&15)][kc = itg*32+(lane>>4)*8+j]
    int pb = bx - 1152;                 // 0..287
    int t = pb*256 + tid;               // 0..73727
    int e0 = t*8;
    int lane = (e0 >> 3) & 63;
    int mi   = (e0 >> 9) & 3;
    int mw   = (e0 >> 11) & 1;
    int rr   = e0 >> 12; int itg = rr % 72; int mo = rr / 72;
    int o = mo*128 + mw*64 + mi*16 + (lane & 15);
    int kcb = itg*32 + (lane >> 4)*8;
    #pragma unroll
    for (int j2 = 0; j2 < 8; j2++) {
      int kc = kcb + j2; int k = kc >> 8; int c = kc & 255;
      float a = w_conv[((size_t)o*C + c)*9 + k];
      u16 hi, lo; split16(a, hi, lo);
      A_hi[e0 + j2] = hi; A_lo[e0 + j2] = lo;
    }

  } else {
    // ---- pack+split stage-A weights into frag-tiled A2 (M=32: 0..17 w_p, 18..20 w_ad, pad 0) ----
    int pb = bx - 1440;                 // 0..35
    int t = pb*256 + tid;               // 0..9215
    int e0 = t*8;
    int lane = (e0 >> 3) & 63;
    int mi   = (e0 >> 9) & 1;
    int itg  = e0 >> 10;                // 0..71
    int o = mi*16 + (lane & 15);
    int kcb = itg*32 + (lane >> 4)*8;
    #pragma unroll
    for (int j2 = 0; j2 < 8; j2++) {
      int kc = kcb + j2; int tap = kc >> 8; int c = kc & 255;
      float a = 0.f;
      if (o < 18)       a = w_p [((size_t)o*C + c)*9 + tap];
      else if (o < 21)  a = w_ad[((size_t)(o-18)*C + c)*9 + tap];
      u16 hi, lo; split16(a, hi, lo);
      A2_hi[e0 + j2] = hi; A2_lo[e0 + j2] = lo;
    }
  }
}

// ================= stage-A conv as split-f16 MFMA: C2[21][NS] = W2 * im2col(xp) =================
// (r11 baseline, untouched — clean A/B on gemm_def this round)
// FULL 3-term split kept here: offsets feed floor()/mask discontinuities, so the
// offset path needs ~1e-5 accuracy (a 2e-4 error can flip a boundary -> 0.3 jump).
// grid 576 = xcd(8) x [kh(2) x sbl(36)]; split-K via atomicAdd into off2 (pre-zeroed).
__global__ __launch_bounds__(256) void conv_mfma(
    const u16* __restrict__ A2_hi, const u16* __restrict__ A2_lo,
    const float* __restrict__ xp, float* __restrict__ off2) {
  __shared__ u16 Bh[2][64*40];
  __shared__ u16 Bl[2][64*40];
  int bx = blockIdx.x;
  int xcd = bx & 7; int jj = bx >> 3;          // jj 0..71
  int kh = jj & 1; int sbl = jj >> 1;          // sbl 0..35
  int sb = xcd*36 + sbl;                       // 0..287
  int s0 = sb * 64;
  int tid = threadIdx.x;
  int wave = tid >> 6, lane = tid & 63;
  int l16 = lane & 15, quad = lane >> 4;

  f32x4 acc[2];
  f32x4 z4 = {0.f, 0.f, 0.f, 0.f};
  acc[0] = z4; acc[1] = z4;

  int s_l = tid >> 2; int cs = (tid & 3) * 8;  // B-build map (r7-r9 proven)
  int sg = s0 + s_l;
  int n = sg / HW; int hw = sg % HW;
  int h = hw / W, w = hw % W;
  const float* sbase = xp + ((size_t)(n*HP + h)*HP + w)*C;   // padded top-left

  for (int it = 0; it < 36; it++) {
    int itg = kh*36 + it;
    int tap = itg >> 3;
    int di = tap / 3, dj = tap % 3;
    int c0k = (itg & 7) * 32;
    // ---- A2 fragments (tiny, L2-hot; identical across waves) ----
    uint4 aH[2], aL[2];
    #pragma unroll
    for (int mi = 0; mi < 2; mi++) {
      size_t off = ((size_t)(itg*2 + mi) << 9) + lane*8;
      aH[mi] = *(const uint4*)(A2_hi + off);
      aL[mi] = *(const uint4*)(A2_lo + off);
    }
    // ---- B2 taps: one contiguous 32B read ----
    const float* p0 = sbase + (di*HP + dj)*C + c0k + cs;
    float4 ta = *(const float4*)(p0), tb = *(const float4*)(p0 + 4);
    float v[8] = {ta.x, ta.y, ta.z, ta.w, tb.x, tb.y, tb.z, tb.w};
    u16 hb[8], lb[8];
    #pragma unroll
    for (int j = 0; j < 8; j++) split16(v[j], hb[j], lb[j]);
    uint4 bph, bpl;
    bph.x = (u32)hb[0] | ((u32)hb[1] << 16); bph.y = (u32)hb[2] | ((u32)hb[3] << 16);
    bph.z = (u32)hb[4] | ((u32)hb[5] << 16); bph.w = (u32)hb[6] | ((u32)hb[7] << 16);
    bpl.x = (u32)lb[0] | ((u32)lb[1] << 16); bpl.y = (u32)lb[2] | ((u32)lb[3] << 16);
    bpl.z = (u32)lb[4] | ((u32)lb[5] << 16); bpl.w = (u32)lb[6] | ((u32)lb[7] << 16);
    int buf = it & 1;
    *(uint4*)(&Bh[buf][s_l*40 + cs]) = bph;
    *(uint4*)(&Bl[buf][s_l*40 + cs]) = bpl;
    sync_lds();
    int rr = (wave*16 + l16)*40 + quad*8;
    f16x8 bfh = *(const f16x8*)(&Bh[buf][rr]);
    f16x8 bfl = *(const f16x8*)(&Bl[buf][rr]);
    #pragma unroll
    for (int mi = 0; mi < 2; mi++) {
      f16x8 fh = __builtin_bit_cast(f16x8, aH[mi]);
      f16x8 fl = __builtin_bit_cast(f16x8, aL[mi]);
      acc[mi] = __builtin_amdgcn_mfma_f32_16x16x32_f16(fh, bfh, acc[mi], 0, 0, 0);
      acc[mi] = __builtin_amdgcn_mfma_f32_16x16x32_f16(fh, bfl, acc[mi], 0, 0, 0);
      acc[mi] = __builtin_amdgcn_mfma_f32_16x16x32_f16(fl, bfh, acc[mi], 0, 0, 0);
    }
  }
  // ---- epilogue: rows <21 accumulate into off2 ----
  int sout = s0 + wave*16 + l16;
  #pragma unroll
  for (int mi = 0; mi < 2; mi++)
    #pragma unroll
    for (int rr2 = 0; rr2 < 4; rr2++) {
      int o = mi*16 + quad*4 + rr2;
      if (o < 21)
        atomicAdd(&off2[(size_t)o*NS + sout], acc[mi][rr2]);
    }
}

// ================= bilinear taps (reads off2 directly) =================
// Kept as a SEPARATE kernel: folding this math into gemm_def changes FP contraction
// (FMA fusion) at the floorf() knife-edges and flips bilinear cells (r8-r10 failures).
__global__ __launch_bounds__(256) void taps2(
    const float* __restrict__ off2, const float* __restrict__ b_p,
    const float* __restrict__ b_ad,
    int* __restrict__ idx_arr, float* __restrict__ g_arr) {
  int e = blockIdx.x * 256 + threadIdx.x;      // < 9*18432 = 165888
  int k = e / NS; int s = e % NS;
  int n = s / HW; int hw = s % HW;
  int h = hw / W, w = hw % W;
  float offx = off2[(size_t)k*NS + s]            + b_p[k];
  float offy = off2[(size_t)(k+9)*NS + s]        + b_p[k+9];
  float za   = off2[(size_t)(18 + (k%3))*NS + s] + b_ad[k % 3];
  float a2 = 2.0f / (1.0f + expf(za));         // (1-sigmoid)*DIL

  float ri = (float)(k / 3) - 1.0f, rj = (float)(k % 3) - 1.0f;
  float px = (float)(h + 1) + ri + offx + a2 * ri;
  float py = (float)(w + 1) + rj + offy + a2 * rj;
  float fx = floorf(px), fy = floorf(py);
  int qltx = min(max((int)fx, 0), 97);
  int qlty = min(max((int)fy, 0), 97);
  int qrbx = min(max((int)fx + 1, 0), 97);
  int qrby = min(max((int)fy + 1, 0), 97);
  bool mx = (px < 1.0f) || (px > 96.0f);
  bool my = (py < 1.0f) || (py > 96.0f);
  float pxm = mx ? fx : px;
  float pym = my ? fy : py;
  pxm = fminf(fmaxf(pxm, 0.f), 97.f);
  pym = fminf(fmaxf(pym, 0.f), 97.f);
  float glx = 1.0f + ((float)qltx - pxm);
  float grx = 1.0f - ((float)qrbx - pxm);
  float gly = 1.0f + ((float)qlty - pym);
  float gry = 1.0f - ((float)qrby - pym);
  int base = n * HP * HP * C;
  int4 qi;
  qi.x = base + (qltx*HP + qlty)*C;   // lt
  qi.y = base + (qrbx*HP + qrby)*C;   // rb
  qi.z = base + (qltx*HP + qrby)*C;   // lb
  qi.w = base + (qrbx*HP + qlty)*C;   // rt
  float4 gg = make_float4(glx*gly, grx*gry, glx*gry, grx*gly);
  *(int4*)(idx_arr + (size_t)e*4) = qi;
  *(float4*)(g_arr  + (size_t)e*4) = gg;
}

// one pipelined gemm step: build taps(IT) from TC/GGC (fetched last iter), write buf(IT&1),
// sync, ds_read, THEN issue taps(IT+1) loads into TN/GGN (hide under MFMA), then 16 MFMA.
// Protocol = r4-proven (passed) minus A-prefetch; LDS order identical to r5/r11 baseline.
#define GSTEP(IT, TC, TN, GGC, GGN) do { \
  int itg_ = kh*36 + (IT); \
  uint4 aH_[4]; \
  int abase_ = ((mo*72 + itg_)*2 + mw)*4; \
  _Pragma("unroll") \
  for (int mi_ = 0; mi_ < 4; mi_++) \
    aH_[mi_] = *(const uint4*)(A_hi + (((size_t)(abase_ + mi_)) << 9) + lane*8); \
  float v0_ = (GGC).x*(TC)[0].x + (GGC).y*(TC)[2].x + (GGC).z*(TC)[4].x + (GGC).w*(TC)[6].x; \
  float v1_ = (GGC).x*(TC)[0].y + (GGC).y*(TC)[2].y + (GGC).z*(TC)[4].y + (GGC).w*(TC)[6].y; \
  float v2_ = (GGC).x*(TC)[0].z + (GGC).y*(TC)[2].z + (GGC).z*(TC)[4].z + (GGC).w*(TC)[6].z; \
  float v3_ = (GGC).x*(TC)[0].w + (GGC).y*(TC)[2].w + (GGC).z*(TC)[4].w + (GGC).w*(TC)[6].w; \
  float v4_ = (GGC).x*(TC)[1].x + (GGC).y*(TC)[3].x + (GGC).z*(TC)[5].x + (GGC).w*(TC)[7].x; \
  float v5_ = (GGC).x*(TC)[1].y + (GGC).y*(TC)[3].y + (GGC).z*(TC)[5].y + (GGC).w*(TC)[7].y; \
  float v6_ = (GGC).x*(TC)[1].z + (GGC).y*(TC)[3].z + (GGC).z*(TC)[5].z + (GGC).w*(TC)[7].z; \
  float v7_ = (GGC).x*(TC)[1].w + (GGC).y*(TC)[3].w + (GGC).z*(TC)[5].w + (GGC).w*(TC)[7].w; \
  uint4 bph_; \
  bph_.x = (u32)h2u((_Float16)v0_) | ((u32)h2u((_Float16)v1_) << 16); \
  bph_.y = (u32)h2u((_Float16)v2_) | ((u32)h2u((_Float16)v3_) << 16); \
  bph_.z = (u32)h2u((_Float16)v4_) | ((u32)h2u((_Float16)v5_) << 16); \
  bph_.w = (u32)h2u((_Float16)v6_) | ((u32)h2u((_Float16)v7_) << 16); \
  *(uint4*)(&Bh[(IT)&1][s_l*40 + cs]) = bph_; \
  sync_lds(); \
  f16x8 bfh_[4]; \
  _Pragma("unroll") \
  for (int ni_ = 0; ni_ < 4; ni_++) \
    bfh_[ni_] = *(const f16x8*)(&Bh[(IT)&1][(ni_*16 + l16)*40 + quad*8]); \
  if ((IT) < 35) { \
    int itn_ = itg_ + 1; \
    if ((itn_ & 7) == 0) { \
      int k_ = itn_ >> 3; \
      qi    = *(const int4*)(idx_arr + ((size_t)k_*NS + sg)*4); \
      (GGN) = *(const float4*)(g_arr  + ((size_t)k_*NS + sg)*4); \
    } else { (GGN) = (GGC); } \
    int c0kn_ = (itn_ & 7) * 32; \
    const float* q0_ = xp + qi.x + c0kn_ + cs; \
    const float* q1_ = xp + qi.y + c0kn_ + cs; \
    const float* q2_ = xp + qi.z + c0kn_ + cs; \
    const float* q3_ = xp + qi.w + c0kn_ + cs; \
    (TN)[0] = *(const float4*)(q0_); (TN)[1] = *(const float4*)(q0_ + 4); \
    (TN)[2] = *(const float4*)(q1_); (TN)[3] = *(const float4*)(q1_ + 4); \
    (TN)[4] = *(const float4*)(q2_); (TN)[5] = *(const float4*)(q2_ + 4); \
    (TN)[6] = *(const float4*)(q3_); (TN)[7] = *(const float4*)(q3_ + 4); \
  } \
  _Pragma("unroll") \
  for (int mi_ = 0; mi_ < 4; mi_++) { \
    f16x8 fh_ = __builtin_bit_cast(f16x8, aH_[mi_]); \
    _Pragma("unroll") \
    for (int ni_ = 0; ni_ < 4; ni_++) \
      acc[mi_][ni_] = __builtin_amdgcn_mfma_f32_16x16x32_f16(fh_, bfh_[ni_], acc[mi_][ni_], 0, 0, 0); \
  } \
} while (0)

// ================= fused gather + PURE-F16 MFMA GEMM, taps-prefetch pipelined =================
// grid 576 = xcd(8) x [kh(2) x sbl(36)]; split-K2 via atomicAdd into out (pre-zeroed).
// Manual x2 unroll with A/B register sets (no rotation copies, no dynamic indexing).
__global__ __launch_bounds__(256) void gemm_def(
    const u16* __restrict__ A_hi,
    const float* __restrict__ xp,
    const int* __restrict__ idx_arr, const float* __restrict__ g_arr,
    float* __restrict__ out) {
  __shared__ u16 Bh[2][64*40];
  int bx = blockIdx.x;
  int xcd = bx & 7; int jj = bx >> 3;          // jj 0..71
  int kh = jj & 1; int sbl = jj >> 1;          // sbl 0..35
  int sb = xcd*36 + sbl;                       // 0..287
  int s0 = sb * 64;
  int n0 = s0 / HW; int hw0 = s0 % HW;
  int tid = threadIdx.x;
  int wave = tid >> 6, lane = tid & 63;
  int l16 = lane & 15, quad = lane >> 4;
  int mo = wave >> 1, mw = wave & 1;           // A-layout frag coords

  f32x4 acc[4][4];
  f32x4 z4 = {0.f, 0.f, 0.f, 0.f};
  #pragma unroll
  for (int i = 0; i < 4; i++)
    { acc[i][0] = z4; acc[i][1] = z4; acc[i][2] = z4; acc[i][3] = z4; }

  int s_l = tid >> 2; int cs = (tid & 3) * 8;  // B-build mapping
  int sg = s0 + s_l;

  int4 qi; float4 ggA, ggB;
  float4 tcA[8], tcB[8];
  // ---- prologue: window(it0) taps into tcA ----
  {
    int itg0 = kh*36;
    int k0 = itg0 >> 3;
    qi  = *(const int4*)(idx_arr + ((size_t)k0*NS + sg)*4);
    ggA = *(const float4*)(g_arr  + ((size_t)k0*NS + sg)*4);
    int c0k0 = (itg0 & 7) * 32;
    const float* q0 = xp + qi.x + c0k0 + cs;
    const float* q1 = xp + qi.y + c0k0 + cs;
    const float* q2 = xp + qi.z + c0k0 + cs;
    const float* q3 = xp + qi.w + c0k0 + cs;
    tcA[0] = *(const float4*)(q0); tcA[1] = *(const float4*)(q0 + 4);
    tcA[2] = *(const float4*)(q1); tcA[3] = *(const float4*)(q1 + 4);
    tcA[4] = *(const float4*)(q2); tcA[5] = *(const float4*)(q2 + 4);
    tcA[6] = *(const float4*)(q3); tcA[7] = *(const float4*)(q3 + 4);
    ggB = ggA;
    #pragma unroll
    for (int j = 0; j < 8; j++) tcB[j] = tcA[j];   // silence uninit; overwritten by GSTEP(0)
  }

  for (int t2 = 0; t2 < 18; t2++) {
    GSTEP(2*t2,     tcA, tcB, ggA, ggB);
    GSTEP(2*t2 + 1, tcB, tcA, ggB, ggA);
  }

  // ---- epilogue: split-K accumulate ----
  #pragma unroll
  for (int mi = 0; mi < 4; mi++)
    #pragma unroll
    for (int ni = 0; ni < 4; ni++) {
      int hw = hw0 + ni*16 + l16;
      #pragma unroll
      for (int rr = 0; rr < 4; rr++) {
        int o = wave*64 + mi*16 + quad*4 + rr;
        atomicAdd(&out[(size_t)(n0*OC + o)*HW + hw], acc[mi][ni][rr]);
      }
    }
}

extern "C" void kernel_launch(void* const* d_in, const int* in_sizes, int n_in,
                              void* d_out, int out_size, void* d_ws, size_t ws_size,
                              hipStream_t stream) {
  const float* x      = (const float*)d_in[0];
  const float* w_p    = (const float*)d_in[1];
  const float* b_p    = (const float*)d_in[2];
  const float* w_ad   = (const float*)d_in[3];
  const float* b_ad   = (const float*)d_in[4];
  const float* w_conv = (const float*)d_in[5];
  float* out = (float*)d_out;

  char* ws = (char*)d_ws;
  float* xp      = (float*)(ws + XP_OFF);
  u16*   A_hi    = (u16*)  (ws + AHI_OFF);
  u16*   A_lo    = (u16*)  (ws + ALO_OFF);
  u16*   A2_hi   = (u16*)  (ws + A2HI_OFF);
  u16*   A2_lo   = (u16*)  (ws + A2LO_OFF);
  float* off2    = (float*)(ws + OFF2_OFF);
  int*   idx_arr = (int*)  (ws + IDX_OFF);
  float* g_arr   = (float*)(ws + G_OFF);

  hipMemsetAsync(xp, 0, (size_t)NB*HP*HP*C*sizeof(float), stream);
  hipMemsetAsync(off2, 0, (size_t)21*NS*sizeof(float), stream);
  hipMemsetAsync(out, 0, (size_t)out_size*sizeof(float), stream);

  prep1    <<<1476, 256, 0, stream>>>(x, w_p, w_ad, w_conv, xp, A_hi, A_lo, A2_hi, A2_lo);
  conv_mfma<<<576,  256, 0, stream>>>(A2_hi, A2_lo, xp, off2);
  taps2    <<<648,  256, 0, stream>>>(off2, b_p, b_ad, idx_arr, g_arr);
  gemm_def <<<576,  256, 0, stream>>>(A_hi, xp, idx_arr, g_arr, out);
}

// Round 13
// 204.296 us; speedup vs baseline: 1.0312x; 1.0312x over previous
//
#include <hip/hip_runtime.h>
#include <math.h>

typedef unsigned short u16;
typedef unsigned int   u32;

typedef __attribute__((ext_vector_type(8))) _Float16 f16x8;
typedef __attribute__((ext_vector_type(4))) float    f32x4;

// ---------- constants ----------
#define NB   2
#define C    256
#define H    96
#define W    96
#define HW   (H*W)          // 9216
#define HP   98
#define OC   256
#define KDIM (9*C)          // 2304
#define NS   (NB*HW)        // 18432 spatial columns

// ws layout (bytes) — xp is now stored SPLIT as two f16 planes (same total bytes)
#define XPH_OFF   0                      // 2*98*98*256 f16  = 9834496
#define XPL_OFF   9834496                // 2*98*98*256 f16  = 9834496
#define AHI_OFF   19668992               // 256*2304 f16     = 1179648
#define ALO_OFF   20848640               // 256*2304 f16     = 1179648
#define A2HI_OFF  22028288               // 32*2304 f16      = 147456
#define A2LO_OFF  22175744               // 32*2304 f16      = 147456
#define OFF2_OFF  22323200               // 21*18432 fp32    = 1548288
#define IDX_OFF   23871488               // 9*18432*4 int    = 2654208
#define G_OFF     26525696               // 9*18432*4 fp32   = 2654208
// end 29179904 (identical to previous layout)

__device__ __forceinline__ u16 h2u(_Float16 h) {
  return __builtin_bit_cast(unsigned short, h);
}
__device__ __forceinline__ void split16(float v, u16& hi, u16& lo) {
  _Float16 h = (_Float16)v;        // v_cvt_f16_f32, RNE
  float r = v - (float)h;          // exact residual
  _Float16 l = (_Float16)r;
  hi = h2u(h); lo = h2u(l);
}
// LDS-only barrier: waits lgkmcnt(0) but does NOT drain vmcnt.
__device__ __forceinline__ void sync_lds() {
  asm volatile("s_waitcnt lgkmcnt(0)\n\ts_barrier" ::: "memory");
}

// ================= prep: pad_pack(0..1151) | pack_A(1152..1439) | pack_A2(1440..1475) =================
// pad_pack now applies split16 ONCE per element and stores f16 hi/lo planes.
// conv_mfma's MFMA operands are therefore BIT-IDENTICAL to the r5 runtime-split version.
__global__ __launch_bounds__(256) void prep1(
    const float* __restrict__ x, const float* __restrict__ w_p,
    const float* __restrict__ w_ad, const float* __restrict__ w_conv,
    u16* __restrict__ xph, u16* __restrict__ xpl,
    u16* __restrict__ A_hi, u16* __restrict__ A_lo,
    u16* __restrict__ A2_hi, u16* __restrict__ A2_lo) {
  __shared__ float smem[64*65];
  int bx = blockIdx.x;
  int tid = threadIdx.x;

  if (bx < 1152) {
    // ---- NCHW fp32 -> padded NHWC split-f16 (borders pre-zeroed by memset) ----
    int pb = bx;
    int n = pb / 576; int r = pb % 576;
    int cb = r / 144; int hwb = r % 144;
    int c0 = cb * 64, hw0 = hwb * 64;
    int ii = tid & 63; int cl4 = tid >> 6;
    #pragma unroll
    for (int r2 = 0; r2 < 16; r2++) {
      int c_l = cl4*16 + r2;
      smem[c_l*65 + ii] = x[(size_t)(n*C + c0 + c_l)*HW + hw0 + ii];
    }
    __syncthreads();
    int hw = hw0 + ii;
    int h = hw / W, w = hw % W;
    size_t base = ((size_t)(n*HP + h + 1)*HP + (w + 1))*C + c0 + cl4*16;
    u16 th[16], tl[16];
    #pragma unroll
    for (int r2 = 0; r2 < 16; r2++)
      split16(smem[(cl4*16 + r2)*65 + ii], th[r2], tl[r2]);
    uint4 ph0, ph1, pl0, pl1;
    ph0.x = (u32)th[0]  | ((u32)th[1]  << 16); ph0.y = (u32)th[2]  | ((u32)th[3]  << 16);
    ph0.z = (u32)th[4]  | ((u32)th[5]  << 16); ph0.w = (u32)th[6]  | ((u32)th[7]  << 16);
    ph1.x = (u32)th[8]  | ((u32)th[9]  << 16); ph1.y = (u32)th[10] | ((u32)th[11] << 16);
    ph1.z = (u32)th[12] | ((u32)th[13] << 16); ph1.w = (u32)th[14] | ((u32)th[15] << 16);
    pl0.x = (u32)tl[0]  | ((u32)tl[1]  << 16); pl0.y = (u32)tl[2]  | ((u32)tl[3]  << 16);
    pl0.z = (u32)tl[4]  | ((u32)tl[5]  << 16); pl0.w = (u32)tl[6]  | ((u32)tl[7]  << 16);
    pl1.x = (u32)tl[8]  | ((u32)tl[9]  << 16); pl1.y = (u32)tl[10] | ((u32)tl[11] << 16);
    pl1.z = (u32)tl[12] | ((u32)tl[13] << 16); pl1.w = (u32)tl[14] | ((u32)tl[15] << 16);
    *(uint4*)(xph + base)     = ph0;
    *(uint4*)(xph + base + 8) = ph1;
    *(uint4*)(xpl + base)     = pl0;
    *(uint4*)(xpl + base + 8) = pl1;

  } else if (bx < 1440) {
    // ---- pack+split w_conv into MFMA-fragment-tiled A_hi/A_lo (r8/r9-proven) ----
    // e = ((((mo*72+itg)*2+mw)*4+mi)*64+lane)*8 + j holds
    //   A[o = mo*128+mw*64+mi*16+(lane&15)][kc = itg*32+(lane>>4)*8+j]
    int pb = bx - 1152;                 // 0..287
    int t = pb*256 + tid;               // 0..73727
    int e0 = t*8;
    int lane = (e0 >> 3) & 63;
    int mi   = (e0 >> 9) & 3;
    int mw   = (e0 >> 11) & 1;
    int rr   = e0 >> 12; int itg = rr % 72; int mo = rr / 72;
    int o = mo*128 + mw*64 + mi*16 + (lane & 15);
    int kcb = itg*32 + (lane >> 4)*8;
    #pragma unroll
    for (int j2 = 0; j2 < 8; j2++) {
      int kc = kcb + j2; int k = kc >> 8; int c = kc & 255;
      float a = w_conv[((size_t)o*C + c)*9 + k];
      u16 hi, lo; split16(a, hi, lo);
      A_hi[e0 + j2] = hi; A_lo[e0 + j2] = lo;
    }

  } else {
    // ---- pack+split stage-A weights into frag-tiled A2 (M=32: 0..17 w_p, 18..20 w_ad, pad 0) ----
    int pb = bx - 1440;                 // 0..35
    int t = pb*256 + tid;               // 0..9215
    int e0 = t*8;
    int lane = (e0 >> 3) & 63;
    int mi   = (e0 >> 9) & 1;
    int itg  = e0 >> 10;                // 0..71
    int o = mi*16 + (lane & 15);
    int kcb = itg*32 + (lane >> 4)*8;
    #pragma unroll
    for (int j2 = 0; j2 < 8; j2++) {
      int kc = kcb + j2; int tap = kc >> 8; int c = kc & 255;
      float a = 0.f;
      if (o < 18)       a = w_p [((size_t)o*C + c)*9 + tap];
      else if (o < 21)  a = w_ad[((size_t)(o-18)*C + c)*9 + tap];
      u16 hi, lo; split16(a, hi, lo);
      A2_hi[e0 + j2] = hi; A2_lo[e0 + j2] = lo;
    }
  }
}

// ================= stage-A conv: register-direct split-f16 MFMA, NO LDS, NO barriers =================
// r6-proven reg-direct structure at r5-proven grid (576, split-K2). B operands are loaded
// directly from the precomputed split planes — bit-identical to the r5 runtime-split MFMA.
// FULL 3-term split kept: offsets feed floor()/mask discontinuities.
__global__ __launch_bounds__(256) void conv_mfma(
    const u16* __restrict__ A2_hi, const u16* __restrict__ A2_lo,
    const u16* __restrict__ xph, const u16* __restrict__ xpl,
    float* __restrict__ off2) {
  int bx = blockIdx.x;
  int xcd = bx & 7; int jj = bx >> 3;          // jj 0..71
  int kh = jj & 1; int sbl = jj >> 1;          // sbl 0..35
  int sb = xcd*36 + sbl;                       // 0..287
  int s0 = sb * 64;
  int tid = threadIdx.x;
  int wave = tid >> 6, lane = tid & 63;
  int l16 = lane & 15, quad = lane >> 4;

  f32x4 acc[2];
  f32x4 z4 = {0.f, 0.f, 0.f, 0.f};
  acc[0] = z4; acc[1] = z4;

  int sg = s0 + wave*16 + l16;                 // this lane's spatial column
  int n = sg / HW; int hw = sg % HW;
  int h = hw / W, w = hw % W;
  size_t sboff = ((size_t)(n*HP + h)*HP + w)*C + quad*8;  // padded top-left + k-slot
  const u16* sbH = xph + sboff;
  const u16* sbL = xpl + sboff;

  for (int it = 0; it < 36; it++) {
    int itg = kh*36 + it;
    int tap = itg >> 3;
    int di = tap / 3, dj = tap % 3;
    int c0k = (itg & 7) * 32;
    // ---- A2 fragments (tiny, L2-hot; identical across waves) ----
    uint4 aH[2], aL[2];
    #pragma unroll
    for (int mi = 0; mi < 2; mi++) {
      size_t off = ((size_t)(itg*2 + mi) << 9) + lane*8;
      aH[mi] = *(const uint4*)(A2_hi + off);
      aL[mi] = *(const uint4*)(A2_lo + off);
    }
    // ---- B fragment: two 16B loads, already split ----
    int toff = (di*HP + dj)*C + c0k;
    f16x8 bfh = *(const f16x8*)(sbH + toff);
    f16x8 bfl = *(const f16x8*)(sbL + toff);
    #pragma unroll
    for (int mi = 0; mi < 2; mi++) {
      f16x8 fh = __builtin_bit_cast(f16x8, aH[mi]);
      f16x8 fl = __builtin_bit_cast(f16x8, aL[mi]);
      acc[mi] = __builtin_amdgcn_mfma_f32_16x16x32_f16(fh, bfh, acc[mi], 0, 0, 0);
      acc[mi] = __builtin_amdgcn_mfma_f32_16x16x32_f16(fh, bfl, acc[mi], 0, 0, 0);
      acc[mi] = __builtin_amdgcn_mfma_f32_16x16x32_f16(fl, bfh, acc[mi], 0, 0, 0);
    }
  }
  // ---- epilogue: rows <21 accumulate into off2 ----
  int sout = s0 + wave*16 + l16;
  #pragma unroll
  for (int mi = 0; mi < 2; mi++)
    #pragma unroll
    for (int rr2 = 0; rr2 < 4; rr2++) {
      int o = mi*16 + quad*4 + rr2;
      if (o < 21)
        atomicAdd(&off2[(size_t)o*NS + sout], acc[mi][rr2]);
    }
}

// ================= bilinear taps (reads off2 directly) =================
// Kept as a SEPARATE kernel: folding this math into gemm_def changes FP contraction
// (FMA fusion) at the floorf() knife-edges and flips bilinear cells (r8-r10 failures).
__global__ __launch_bounds__(256) void taps2(
    const float* __restrict__ off2, const float* __restrict__ b_p,
    const float* __restrict__ b_ad,
    int* __restrict__ idx_arr, float* __restrict__ g_arr) {
  int e = blockIdx.x * 256 + threadIdx.x;      // < 9*18432 = 165888
  int k = e / NS; int s = e % NS;
  int n = s / HW; int hw = s % HW;
  int h = hw / W, w = hw % W;
  float offx = off2[(size_t)k*NS + s]            + b_p[k];
  float offy = off2[(size_t)(k+9)*NS + s]        + b_p[k+9];
  float za   = off2[(size_t)(18 + (k%3))*NS + s] + b_ad[k % 3];
  float a2 = 2.0f / (1.0f + expf(za));         // (1-sigmoid)*DIL

  float ri = (float)(k / 3) - 1.0f, rj = (float)(k % 3) - 1.0f;
  float px = (float)(h + 1) + ri + offx + a2 * ri;
  float py = (float)(w + 1) + rj + offy + a2 * rj;
  float fx = floorf(px), fy = floorf(py);
  int qltx = min(max((int)fx, 0), 97);
  int qlty = min(max((int)fy, 0), 97);
  int qrbx = min(max((int)fx + 1, 0), 97);
  int qrby = min(max((int)fy + 1, 0), 97);
  bool mx = (px < 1.0f) || (px > 96.0f);
  bool my = (py < 1.0f) || (py > 96.0f);
  float pxm = mx ? fx : px;
  float pym = my ? fy : py;
  pxm = fminf(fmaxf(pxm, 0.f), 97.f);
  pym = fminf(fmaxf(pym, 0.f), 97.f);
  float glx = 1.0f + ((float)qltx - pxm);
  float grx = 1.0f - ((float)qrbx - pxm);
  float gly = 1.0f + ((float)qlty - pym);
  float gry = 1.0f - ((float)qrby - pym);
  int base = n * HP * HP * C;
  int4 qi;
  qi.x = base + (qltx*HP + qlty)*C;   // lt
  qi.y = base + (qrbx*HP + qrby)*C;   // rb
  qi.z = base + (qltx*HP + qrby)*C;   // lb
  qi.w = base + (qrbx*HP + qlty)*C;   // rt
  float4 gg = make_float4(glx*gly, grx*gry, glx*gry, grx*gly);
  *(int4*)(idx_arr + (size_t)e*4) = qi;
  *(float4*)(g_arr  + (size_t)e*4) = gg;
}

// ================= fused gather + PURE-F16 MFMA GEMM, M=256 (r5/r11-proven BK=32 body) =================
// Only change vs r11: taps load 16B f16 (xp_h) instead of 32B f32 — halves gather bytes,
// gather band now fits per-XCD L2. Added error ~2^-12/term -> ~2e-4 on output (smooth path).
// grid 576 = xcd(8) x [kh(2) x sbl(36)]; split-K2 via atomicAdd into out (pre-zeroed).
__global__ __launch_bounds__(256) void gemm_def(
    const u16* __restrict__ A_hi,
    const u16* __restrict__ xph,
    const int* __restrict__ idx_arr, const float* __restrict__ g_arr,
    float* __restrict__ out) {
  __shared__ u16 Bh[2][64*40];
  int bx = blockIdx.x;
  int xcd = bx & 7; int jj = bx >> 3;          // jj 0..71
  int kh = jj & 1; int sbl = jj >> 1;          // sbl 0..35
  int sb = xcd*36 + sbl;                       // 0..287
  int s0 = sb * 64;
  int n = s0 / HW; int hw0 = s0 % HW;
  int tid = threadIdx.x;
  int wave = tid >> 6, lane = tid & 63;
  int l16 = lane & 15, quad = lane >> 4;
  int mo = wave >> 1, mw = wave & 1;           // A-layout frag coords

  f32x4 acc[4][4];
  f32x4 z4 = {0.f, 0.f, 0.f, 0.f};
  #pragma unroll
  for (int i = 0; i < 4; i++)
    { acc[i][0] = z4; acc[i][1] = z4; acc[i][2] = z4; acc[i][3] = z4; }

  int s_l = tid >> 2; int cs = (tid & 3) * 8;  // B-build mapping
  int sg = s0 + s_l;

  int4 qi; float4 gg;
  for (int it = 0; it < 36; it++) {
    int itg = kh*36 + it;
    int c0k = (itg & 7) * 32;
    if (it == 0 || (itg & 7) == 0) {           // qi/g hoisted per k-window
      int k = itg >> 3;
      qi = *(const int4*)(idx_arr + ((size_t)k*NS + sg)*4);
      gg = *(const float4*)(g_arr  + ((size_t)k*NS + sg)*4);
    }
    // ---- A fragments direct from global (coalesced 16B/lane, L2-hot), hi only ----
    uint4 aH[4];
    int abase = ((mo*72 + itg)*2 + mw)*4;
    #pragma unroll
    for (int mi = 0; mi < 4; mi++) {
      size_t off = ((size_t)(abase + mi) << 9) + lane*8;
      aH[mi] = *(const uint4*)(A_hi + off);
    }
    // ---- taps: 4x 16B f16 loads (halved gather bytes) ----
    f16x8 t0 = *(const f16x8*)(xph + qi.x + c0k + cs);
    f16x8 t1 = *(const f16x8*)(xph + qi.y + c0k + cs);
    f16x8 t2 = *(const f16x8*)(xph + qi.z + c0k + cs);
    f16x8 t3 = *(const f16x8*)(xph + qi.w + c0k + cs);
    u16 hb[8];
    #pragma unroll
    for (int j = 0; j < 8; j++) {
      float v = gg.x*(float)t0[j] + gg.y*(float)t1[j] + gg.z*(float)t2[j] + gg.w*(float)t3[j];
      hb[j] = h2u((_Float16)v);
    }
    uint4 bph;
    bph.x = (u32)hb[0] | ((u32)hb[1] << 16); bph.y = (u32)hb[2] | ((u32)hb[3] << 16);
    bph.z = (u32)hb[4] | ((u32)hb[5] << 16); bph.w = (u32)hb[6] | ((u32)hb[7] << 16);
    int buf = it & 1;
    *(uint4*)(&Bh[buf][s_l*40 + cs]) = bph;
    sync_lds();   // single barrier/iter (proven protocol)
    f16x8 bfh[4];
    #pragma unroll
    for (int ni = 0; ni < 4; ni++) {
      int rr = (ni*16 + l16)*40 + quad*8;
      bfh[ni] = *(const f16x8*)(&Bh[buf][rr]);
    }
    #pragma unroll
    for (int mi = 0; mi < 4; mi++) {
      f16x8 fh = __builtin_bit_cast(f16x8, aH[mi]);
      #pragma unroll
      for (int ni = 0; ni < 4; ni++) {
        acc[mi][ni] = __builtin_amdgcn_mfma_f32_16x16x32_f16(fh, bfh[ni], acc[mi][ni], 0, 0, 0);
      }
    }
  }
  // ---- epilogue: split-K accumulate ----
  #pragma unroll
  for (int mi = 0; mi < 4; mi++)
    #pragma unroll
    for (int ni = 0; ni < 4; ni++) {
      int hw = hw0 + ni*16 + l16;
      #pragma unroll
      for (int rr = 0; rr < 4; rr++) {
        int o = wave*64 + mi*16 + quad*4 + rr;
        atomicAdd(&out[(size_t)(n*OC + o)*HW + hw], acc[mi][ni][rr]);
      }
    }
}

extern "C" void kernel_launch(void* const* d_in, const int* in_sizes, int n_in,
                              void* d_out, int out_size, void* d_ws, size_t ws_size,
                              hipStream_t stream) {
  const float* x      = (const float*)d_in[0];
  const float* w_p    = (const float*)d_in[1];
  const float* b_p    = (const float*)d_in[2];
  const float* w_ad   = (const float*)d_in[3];
  const float* b_ad   = (const float*)d_in[4];
  const float* w_conv = (const float*)d_in[5];
  float* out = (float*)d_out;

  char* ws = (char*)d_ws;
  u16*   xph     = (u16*)  (ws + XPH_OFF);
  u16*   xpl     = (u16*)  (ws + XPL_OFF);
  u16*   A_hi    = (u16*)  (ws + AHI_OFF);
  u16*   A_lo    = (u16*)  (ws + ALO_OFF);
  u16*   A2_hi   = (u16*)  (ws + A2HI_OFF);
  u16*   A2_lo   = (u16*)  (ws + A2LO_OFF);
  float* off2    = (float*)(ws + OFF2_OFF);
  int*   idx_arr = (int*)  (ws + IDX_OFF);
  float* g_arr   = (float*)(ws + G_OFF);

  hipMemsetAsync(xph, 0, (size_t)NB*HP*HP*C*sizeof(u16), stream);
  hipMemsetAsync(xpl, 0, (size_t)NB*HP*HP*C*sizeof(u16), stream);
  hipMemsetAsync(off2, 0, (size_t)21*NS*sizeof(float), stream);
  hipMemsetAsync(out, 0, (size_t)out_size*sizeof(float), stream);

  prep1    <<<1476, 256, 0, stream>>>(x, w_p, w_ad, w_conv, xph, xpl, A_hi, A_lo, A2_hi, A2_lo);
  conv_mfma<<<576,  256, 0, stream>>>(A2_hi, A2_lo, xph, xpl, off2);
  taps2    <<<648,  256, 0, stream>>>(off2, b_p, b_ad, idx_arr, g_arr);
  gemm_def <<<576,  256, 0, stream>>>(A_hi, xph, idx_arr, g_arr, out);
}